// Round 2
// baseline (170.960 us; speedup 1.0000x reference)
//
#include <hip/hip_runtime.h>
#include <math.h>

#define N_OBJ 8192
#define N_SR  4096
#define N_V   4100
#define N_F   4096
#define EPSF  1e-8f

#define SR_CHUNK   512
#define N_SRCH     (N_SR / SR_CHUNK)     // 8
#define FACE_CHUNK 256
#define N_FCH      (N_F / FACE_CHUNK)    // 16

// ---------------- Kernel 0: precompute (sr4 table, face table, zero hits) ----
// grid: 16 blocks x 256 = 4096 threads (== N_F == N_SR)
__global__ void __launch_bounds__(256) pre(const float* __restrict__ hv,
                                           const float* __restrict__ fn,
                                           const int* __restrict__ hf,
                                           const float* __restrict__ sr,
                                           float4* __restrict__ F,
                                           float4* __restrict__ sr4,
                                           int* __restrict__ hits) {
    const int f = blockIdx.x * 256 + threadIdx.x;   // 0..4095

    // sr4 table: (x,y,z,|s|^2)
    {
        float sx = sr[3 * f + 0], sy = sr[3 * f + 1], sz = sr[3 * f + 2];
        sr4[f] = make_float4(sx, sy, sz, sx * sx + sy * sy + sz * sz);
    }
    // zero hit counters (8192 = 2 per thread)
    hits[2 * f + 0] = 0;
    hits[2 * f + 1] = 0;

    // face precompute: 16 floats/face
    const int i0 = hf[3 * f + 0], i1 = hf[3 * f + 1], i2 = hf[3 * f + 2];
    const float v0x = hv[3 * i0 + 0], v0y = hv[3 * i0 + 1], v0z = hv[3 * i0 + 2];
    const float v1x = hv[3 * i1 + 0], v1y = hv[3 * i1 + 1], v1z = hv[3 * i1 + 2];
    const float v2x = hv[3 * i2 + 0], v2y = hv[3 * i2 + 1], v2z = hv[3 * i2 + 2];
    const float nx = fn[3 * f + 0], ny = fn[3 * f + 1], nz = fn[3 * f + 2];

    F[4 * f + 0] = make_float4(nx, ny, nz, v0x * nx + v0y * ny + v0z * nz);
    {
        float ex = v1x - v0x, ey = v1y - v0y, ez = v1z - v0z;
        float cx = ny * ez - nz * ey, cy = nz * ex - nx * ez, cz = nx * ey - ny * ex;
        F[4 * f + 1] = make_float4(cx, cy, cz, v0x * cx + v0y * cy + v0z * cz);
    }
    {
        float ex = v2x - v1x, ey = v2y - v1y, ez = v2z - v1z;
        float cx = ny * ez - nz * ey, cy = nz * ex - nx * ez, cz = nx * ey - ny * ex;
        F[4 * f + 2] = make_float4(cx, cy, cz, v1x * cx + v1y * cy + v1z * cz);
    }
    {
        float ex = v0x - v2x, ey = v0y - v2y, ez = v0z - v2z;
        float cx = ny * ez - nz * ey, cy = nz * ex - nx * ez, cz = nx * ey - ny * ex;
        F[4 * f + 3] = make_float4(cx, cy, cz, v2x * cx + v2y * cy + v2z * cz);
    }
}

// ---------------- Kernel 1a: partial NN (obj-block x sr-chunk) ----------------
// sr4 read at wave-uniform index -> scalar loads, operands fold into VALU
__global__ void __launch_bounds__(256) nn_partial(const float* __restrict__ obj,
                                                  const float4* __restrict__ sr4,
                                                  float* __restrict__ pd2,
                                                  int* __restrict__ pidx) {
    const int tid = threadIdx.x;
    const int ob = blockIdx.x * 256 + tid;
    const int sbase = blockIdx.y * SR_CHUNK;

    const float ox = obj[3 * ob + 0], oy = obj[3 * ob + 1], oz = obj[3 * ob + 2];
    const float oo = ox * ox + oy * oy + oz * oz;

    float best = INFINITY;
    int bidx = sbase;
#pragma unroll 8
    for (int j = 0; j < SR_CHUNK; ++j) {
        float4 s = sr4[sbase + j];                // uniform -> s_load
        float d = fmaf(s.z, oz, fmaf(s.y, oy, s.x * ox));
        float d2 = fmaf(-2.0f, d, oo + s.w);
        if (d2 < best) { best = d2; bidx = sbase + j; }   // strict < keeps first idx
    }
    pd2[blockIdx.y * N_OBJ + ob] = best;
    pidx[blockIdx.y * N_OBJ + ob] = bidx;
}

// ---------------- Kernel 1b: merge partials, cmap, D-vector ----------------
__global__ void __launch_bounds__(256) nn_finish(const float* __restrict__ obj,
                                                 const float* __restrict__ sr,
                                                 const float* __restrict__ pd2,
                                                 const int* __restrict__ pidx,
                                                 float* __restrict__ out,
                                                 float4* __restrict__ Dws) {
    const int i = blockIdx.x * 256 + threadIdx.x;
    float best = INFINITY;
    int bidx = 0;
#pragma unroll
    for (int c = 0; c < N_SRCH; ++c) {            // ascending chunk: ties -> earliest
        float d = pd2[c * N_OBJ + i];
        if (d < best) { best = d; bidx = pidx[c * N_OBJ + i]; }
    }
    const float ox = obj[3 * i + 0], oy = obj[3 * i + 1], oz = obj[3 * i + 2];
    const float dx = sr[3 * bidx + 0] - ox;
    const float dy = sr[3 * bidx + 1] - oy;
    const float dz = sr[3 * bidx + 2] - oz;
    Dws[i] = make_float4(dx, dy, dz, dx * dx + dy * dy + dz * dz);

    float nn = sqrtf(fmaxf(best, 0.0f));
    float sig = 1.0f / (1.0f + expf(-100.0f * nn));
    out[1 + i] = 1.0f - 2.0f * (sig - 0.5f);
}

// ---------------- Kernel 2: ray-triangle parity counts (division-free) -------
// hit  <=>  dn>EPS  &&  nm>EPS*dn  &&  min_i(C_i . w - s_i*dn) >= 0
// where dn=|denom|, nm=num*sign(denom), w = o*dn + nm*D
__global__ void __launch_bounds__(256) ray_count(const float* __restrict__ obj,
                                                 const float4* __restrict__ Dws,
                                                 const float4* __restrict__ F,
                                                 int* __restrict__ hits) {
    const int tid = threadIdx.x;
    const int ob = blockIdx.x * 256 + tid;
    const float4* __restrict__ Fp = F + (size_t)blockIdx.y * FACE_CHUNK * 4;

    const float ox = obj[3 * ob + 0], oy = obj[3 * ob + 1], oz = obj[3 * ob + 2];
    const float4 Dv = Dws[ob];
    const float dx = Dv.x, dy = Dv.y, dz = Dv.z;

    int cnt = 0;
#pragma unroll 4
    for (int f = 0; f < FACE_CHUNK; ++f) {
        float4 Fn = Fp[4 * f + 0];                // uniform -> s_load, SGPR operands
        float4 C1 = Fp[4 * f + 1];
        float4 C2 = Fp[4 * f + 2];
        float4 C3 = Fp[4 * f + 3];

        float denom = fmaf(Fn.z, dz, fmaf(Fn.y, dy, Fn.x * dx));
        float no    = fmaf(Fn.z, oz, fmaf(Fn.y, oy, Fn.x * ox));
        float num   = Fn.w - no;

        float dn = fabsf(denom);
        float nm = copysignf(num, num * denom);   // num * sign(denom)

        float wx = fmaf(ox, dn, nm * dx);
        float wy = fmaf(oy, dn, nm * dy);
        float wz = fmaf(oz, dn, nm * dz);

        float q1 = fmaf(-C1.w, dn, fmaf(C1.z, wz, fmaf(C1.y, wy, C1.x * wx)));
        float q2 = fmaf(-C2.w, dn, fmaf(C2.z, wz, fmaf(C2.y, wy, C2.x * wx)));
        float q3 = fmaf(-C3.w, dn, fmaf(C3.z, wz, fmaf(C3.y, wy, C3.x * wx)));

        float m  = fminf(q1, fminf(q2, q3));
        float c2 = fmaf(-EPSF, dn, nm);           // nm - EPS*dn

        cnt += ((m >= 0.0f) && (c2 > 0.0f) && (dn > EPSF)) ? 1 : 0;
    }
    atomicAdd(&hits[ob], cnt);
}

// ---------------- Kernel 3: pen_dist reduction (deterministic, 1 block) ------
__global__ void __launch_bounds__(256) finalize(const float4* __restrict__ Dws,
                                                const int* __restrict__ hits,
                                                float* __restrict__ out) {
    __shared__ float wsum[4];
    const int tid = threadIdx.x;
    float s = 0.0f;
    for (int k = tid; k < N_OBJ; k += 256) {
        if (hits[k] & 1) s += Dws[k].w;
    }
#pragma unroll
    for (int off = 32; off > 0; off >>= 1) s += __shfl_down(s, off);
    if ((tid & 63) == 0) wsum[tid >> 6] = s;
    __syncthreads();
    if (tid == 0) {
        float tot = wsum[0] + wsum[1] + wsum[2] + wsum[3];
        out[0] = sqrtf(tot + 1e-12f);
    }
}

extern "C" void kernel_launch(void* const* d_in, const int* in_sizes, int n_in,
                              void* d_out, int out_size, void* d_ws, size_t ws_size,
                              hipStream_t stream) {
    const float* obj = (const float*)d_in[0];
    const float* sr  = (const float*)d_in[1];
    const float* hv  = (const float*)d_in[2];
    const float* fn  = (const float*)d_in[3];
    const int*   hf  = (const int*)d_in[4];
    float* out = (float*)d_out;

    char* ws = (char*)d_ws;
    float4* Dws  = (float4*)(ws + 0);               // 8192*16        = 128 KB
    int*    hits = (int*)  (ws + 131072);           // 8192*4         =  32 KB
    float*  pd2  = (float*)(ws + 163840);           // 8*8192*4       = 256 KB
    int*    pidx = (int*)  (ws + 425984);           // 8*8192*4       = 256 KB
    float4* F    = (float4*)(ws + 688128);          // 4096*4*16      = 256 KB
    float4* sr4  = (float4*)(ws + 950272);          // 4096*16        =  64 KB
                                                    // total 992 KB

    pre<<<N_F / 256, 256, 0, stream>>>(hv, fn, hf, sr, F, sr4, hits);
    nn_partial<<<dim3(N_OBJ / 256, N_SRCH), 256, 0, stream>>>(obj, sr4, pd2, pidx);
    nn_finish<<<N_OBJ / 256, 256, 0, stream>>>(obj, sr, pd2, pidx, out, Dws);
    ray_count<<<dim3(N_OBJ / 256, N_FCH), 256, 0, stream>>>(obj, Dws, F, hits);
    finalize<<<1, 256, 0, stream>>>(Dws, hits, out);
}

// Round 3
// 128.009 us; speedup vs baseline: 1.3355x; 1.3355x over previous
//
#include <hip/hip_runtime.h>
#include <math.h>

#define N_OBJ 8192
#define N_SR  4096
#define N_V   4100
#define N_F   4096
#define EPSF  1e-8f

#define SR_CHUNK   512
#define N_SRCH     (N_SR / SR_CHUNK)       // 8
#define FACE_CHUNK 64
#define N_FCH      (N_F / FACE_CHUNK)      // 64

// ---------------- K1: fused NN-partials + face precompute + hits zero -------
// grid (32, 9): y<8 -> NN partial for sr-chunk y (LDS-staged, broadcast reads)
//               y==8 -> build face table F (128 faces/block) + zero hits
__global__ void __launch_bounds__(256) k_pre_nn(const float* __restrict__ obj,
                                                const float* __restrict__ sr,
                                                const float* __restrict__ hv,
                                                const float* __restrict__ fn,
                                                const int* __restrict__ hf,
                                                float* __restrict__ pd2,
                                                int* __restrict__ pidx,
                                                float4* __restrict__ F,
                                                int* __restrict__ hits) {
    const int tid = threadIdx.x;

    if (blockIdx.y == N_SRCH) {
        hits[blockIdx.x * 256 + tid] = 0;
        if (tid < 128) {
            const int f = blockIdx.x * 128 + tid;
            const int i0 = hf[3 * f + 0], i1 = hf[3 * f + 1], i2 = hf[3 * f + 2];
            const float v0x = hv[3 * i0 + 0], v0y = hv[3 * i0 + 1], v0z = hv[3 * i0 + 2];
            const float v1x = hv[3 * i1 + 0], v1y = hv[3 * i1 + 1], v1z = hv[3 * i1 + 2];
            const float v2x = hv[3 * i2 + 0], v2y = hv[3 * i2 + 1], v2z = hv[3 * i2 + 2];
            const float nx = fn[3 * f + 0], ny = fn[3 * f + 1], nz = fn[3 * f + 2];

            F[4 * f + 0] = make_float4(nx, ny, nz, v0x * nx + v0y * ny + v0z * nz);
            {
                float ex = v1x - v0x, ey = v1y - v0y, ez = v1z - v0z;
                float cx = ny * ez - nz * ey, cy = nz * ex - nx * ez, cz = nx * ey - ny * ex;
                F[4 * f + 1] = make_float4(cx, cy, cz, v0x * cx + v0y * cy + v0z * cz);
            }
            {
                float ex = v2x - v1x, ey = v2y - v1y, ez = v2z - v1z;
                float cx = ny * ez - nz * ey, cy = nz * ex - nx * ez, cz = nx * ey - ny * ex;
                F[4 * f + 2] = make_float4(cx, cy, cz, v1x * cx + v1y * cy + v1z * cz);
            }
            {
                float ex = v0x - v2x, ey = v0y - v2y, ez = v0z - v2z;
                float cx = ny * ez - nz * ey, cy = nz * ex - nx * ez, cz = nx * ey - ny * ex;
                F[4 * f + 3] = make_float4(cx, cy, cz, v2x * cx + v2y * cy + v2z * cz);
            }
        }
        return;
    }

    __shared__ float4 s_sr[SR_CHUNK];
    const int sbase = blockIdx.y * SR_CHUNK;
#pragma unroll
    for (int i = 0; i < SR_CHUNK / 256; ++i) {
        int jj = i * 256 + tid;
        int j = sbase + jj;
        float sx = sr[3 * j + 0], sy = sr[3 * j + 1], sz = sr[3 * j + 2];
        s_sr[jj] = make_float4(sx, sy, sz, sx * sx + sy * sy + sz * sz);
    }
    __syncthreads();

    const int ob = blockIdx.x * 256 + tid;
    const float ox = obj[3 * ob + 0], oy = obj[3 * ob + 1], oz = obj[3 * ob + 2];
    const float oo = ox * ox + oy * oy + oz * oz;

    float best = INFINITY;
    int bidx = sbase;
#pragma unroll 8
    for (int j = 0; j < SR_CHUNK; ++j) {
        float4 s = s_sr[j];                        // wave-uniform -> LDS broadcast
        float d = fmaf(s.z, oz, fmaf(s.y, oy, s.x * ox));
        float d2 = fmaf(-2.0f, d, oo + s.w);
        if (d2 < best) { best = d2; bidx = sbase + j; }   // strict < -> first index
    }
    pd2[blockIdx.y * N_OBJ + ob] = best;
    pidx[blockIdx.y * N_OBJ + ob] = bidx;
}

// ---------------- K2: merge partials, cmap, D-vector ------------------------
__global__ void __launch_bounds__(256) k_merge(const float* __restrict__ obj,
                                               const float* __restrict__ sr,
                                               const float* __restrict__ pd2,
                                               const int* __restrict__ pidx,
                                               float* __restrict__ out,
                                               float4* __restrict__ Dws) {
    const int i = blockIdx.x * 256 + threadIdx.x;
    float best = INFINITY;
    int bidx = 0;
#pragma unroll
    for (int c = 0; c < N_SRCH; ++c) {             // ascending: ties -> earliest
        float d = pd2[c * N_OBJ + i];
        if (d < best) { best = d; bidx = pidx[c * N_OBJ + i]; }
    }
    const float ox = obj[3 * i + 0], oy = obj[3 * i + 1], oz = obj[3 * i + 2];
    const float dx = sr[3 * bidx + 0] - ox;
    const float dy = sr[3 * bidx + 1] - oy;
    const float dz = sr[3 * bidx + 2] - oz;
    Dws[i] = make_float4(dx, dy, dz, dx * dx + dy * dy + dz * dz);

    float nn = sqrtf(fmaxf(best, 0.0f));
    float sig = 1.0f / (1.0f + expf(-100.0f * nn));
    out[1 + i] = 1.0f - 2.0f * (sig - 0.5f);
}

// ---------------- K3: ray-triangle parity counts (division-free, LDS faces) -
// hit <=> dn>EPS && nm>EPS*dn && min_i(C_i.w - s_i*dn) >= 0
// dn=|denom|, nm=num*sign(denom), w = o*dn + nm*D
// 2 obj points per thread, 64-face chunks in LDS (broadcast reads)
__global__ void __launch_bounds__(256) ray_count(const float* __restrict__ obj,
                                                 const float4* __restrict__ Dws,
                                                 const float4* __restrict__ F,
                                                 int* __restrict__ hits) {
    __shared__ float4 sF[FACE_CHUNK * 4];          // 4 KB
    const int tid = threadIdx.x;
    {
        const float* Ff = (const float*)(F + (size_t)blockIdx.y * FACE_CHUNK * 4);
        float* sf = (float*)sF;
#pragma unroll
        for (int i = 0; i < FACE_CHUNK * 16 / 256; ++i)
            sf[i * 256 + tid] = Ff[i * 256 + tid];
    }
    __syncthreads();

    const int p0 = blockIdx.x * 512 + tid;
    const int p1 = p0 + 256;

    const float ax = obj[3 * p0 + 0], ay = obj[3 * p0 + 1], az = obj[3 * p0 + 2];
    const float bx = obj[3 * p1 + 0], by = obj[3 * p1 + 1], bz = obj[3 * p1 + 2];
    const float4 Da = Dws[p0];
    const float4 Db = Dws[p1];

    int ca = 0, cb = 0;
#pragma unroll 4
    for (int f = 0; f < FACE_CHUNK; ++f) {
        const float4 Fn = sF[4 * f + 0];           // broadcast
        const float4 C1 = sF[4 * f + 1];
        const float4 C2 = sF[4 * f + 2];
        const float4 C3 = sF[4 * f + 3];

        // ---- point a ----
        {
            float denom = fmaf(Fn.z, Da.z, fmaf(Fn.y, Da.y, Fn.x * Da.x));
            float num   = Fn.w - fmaf(Fn.z, az, fmaf(Fn.y, ay, Fn.x * ax));
            float dn = fabsf(denom);
            float nm = copysignf(num, num * denom);
            float wx = fmaf(ax, dn, nm * Da.x);
            float wy = fmaf(ay, dn, nm * Da.y);
            float wz = fmaf(az, dn, nm * Da.z);
            float q1 = fmaf(-C1.w, dn, fmaf(C1.z, wz, fmaf(C1.y, wy, C1.x * wx)));
            float q2 = fmaf(-C2.w, dn, fmaf(C2.z, wz, fmaf(C2.y, wy, C2.x * wx)));
            float q3 = fmaf(-C3.w, dn, fmaf(C3.z, wz, fmaf(C3.y, wy, C3.x * wx)));
            float m  = fminf(q1, fminf(q2, q3));
            float c2 = fmaf(-EPSF, dn, nm);
            ca += ((m >= 0.0f) && (c2 > 0.0f) && (dn > EPSF)) ? 1 : 0;
        }
        // ---- point b ----
        {
            float denom = fmaf(Fn.z, Db.z, fmaf(Fn.y, Db.y, Fn.x * Db.x));
            float num   = Fn.w - fmaf(Fn.z, bz, fmaf(Fn.y, by, Fn.x * bx));
            float dn = fabsf(denom);
            float nm = copysignf(num, num * denom);
            float wx = fmaf(bx, dn, nm * Db.x);
            float wy = fmaf(by, dn, nm * Db.y);
            float wz = fmaf(bz, dn, nm * Db.z);
            float q1 = fmaf(-C1.w, dn, fmaf(C1.z, wz, fmaf(C1.y, wy, C1.x * wx)));
            float q2 = fmaf(-C2.w, dn, fmaf(C2.z, wz, fmaf(C2.y, wy, C2.x * wx)));
            float q3 = fmaf(-C3.w, dn, fmaf(C3.z, wz, fmaf(C3.y, wy, C3.x * wx)));
            float m  = fminf(q1, fminf(q2, q3));
            float c2 = fmaf(-EPSF, dn, nm);
            cb += ((m >= 0.0f) && (c2 > 0.0f) && (dn > EPSF)) ? 1 : 0;
        }
    }
    atomicAdd(&hits[p0], ca);
    atomicAdd(&hits[p1], cb);
}

// ---------------- K4: pen_dist reduction (deterministic, 1 block) -----------
__global__ void __launch_bounds__(256) finalize(const float4* __restrict__ Dws,
                                                const int* __restrict__ hits,
                                                float* __restrict__ out) {
    __shared__ float wsum[4];
    const int tid = threadIdx.x;
    float s = 0.0f;
#pragma unroll 8
    for (int k = tid; k < N_OBJ; k += 256) {
        if (hits[k] & 1) s += Dws[k].w;
    }
#pragma unroll
    for (int off = 32; off > 0; off >>= 1) s += __shfl_down(s, off);
    if ((tid & 63) == 0) wsum[tid >> 6] = s;
    __syncthreads();
    if (tid == 0) {
        float tot = wsum[0] + wsum[1] + wsum[2] + wsum[3];
        out[0] = sqrtf(tot + 1e-12f);
    }
}

extern "C" void kernel_launch(void* const* d_in, const int* in_sizes, int n_in,
                              void* d_out, int out_size, void* d_ws, size_t ws_size,
                              hipStream_t stream) {
    const float* obj = (const float*)d_in[0];
    const float* sr  = (const float*)d_in[1];
    const float* hv  = (const float*)d_in[2];
    const float* fn  = (const float*)d_in[3];
    const int*   hf  = (const int*)d_in[4];
    float* out = (float*)d_out;

    char* ws = (char*)d_ws;
    float4* Dws  = (float4*)(ws + 0);              // 8192*16   = 128 KB
    int*    hits = (int*)  (ws + 131072);          // 8192*4    =  32 KB
    float*  pd2  = (float*)(ws + 163840);          // 8*8192*4  = 256 KB
    int*    pidx = (int*)  (ws + 425984);          // 8*8192*4  = 256 KB
    float4* F    = (float4*)(ws + 688128);         // 4096*4*16 = 256 KB
                                                   // total 928 KB

    k_pre_nn<<<dim3(N_OBJ / 256, N_SRCH + 1), 256, 0, stream>>>(obj, sr, hv, fn, hf,
                                                                pd2, pidx, F, hits);
    k_merge<<<N_OBJ / 256, 256, 0, stream>>>(obj, sr, pd2, pidx, out, Dws);
    ray_count<<<dim3(N_OBJ / 512, N_FCH), 256, 0, stream>>>(obj, Dws, F, hits);
    finalize<<<1, 256, 0, stream>>>(Dws, hits, out);
}